// Round 5
// baseline (3250.750 us; speedup 1.0000x reference)
//
#include <hip/hip_runtime.h>

#define NXN 96            // nodes per side
#define NNODE (NXN*NXN)   // 9216
#define NCW 95            // cells per side
#define NTHREADS 1024
#define NWAVES (NTHREADS/64)
#define MAXIT 4000
#define TOL_REL 1e-6
#define STALL_WIN 64      // break if no new gamma-min for this many iters

__device__ __forceinline__ void dual_warp_red(double& a, double& b){
  #pragma unroll
  for (int off = 32; off > 0; off >>= 1){
    a += __shfl_down(a, off, 64);   // two independent chains overlap
    b += __shfl_down(b, off, 64);
  }
}

__device__ __forceinline__ double sum16_tree(const double* buf){
  double t0 = buf[0]  + buf[1],  t1 = buf[2]  + buf[3];
  double t2 = buf[4]  + buf[5],  t3 = buf[6]  + buf[7];
  double t4 = buf[8]  + buf[9],  t5 = buf[10] + buf[11];
  double t6 = buf[12] + buf[13], t7 = buf[14] + buf[15];
  double u0 = t0 + t1, u1 = t2 + t3, u2 = t4 + t5, u3 = t6 + t7;
  return (u0 + u1) + (u2 + u3);
}

__global__ __launch_bounds__(NTHREADS, 1)
void fem_cg_kernel(const float* __restrict__ mask, float* __restrict__ out){
  __shared__ float  s_buf0[NNODE];       // publish buffers, parity-alternated
  __shared__ float  s_buf1[NNODE];
  __shared__ double s_gA[2][NWAVES];     // parity-alternated partials
  __shared__ double s_gB[2][NWAVES];
  const int tid = threadIdx.x, lane = tid & 63, wid = tid >> 6;
  const int bx = tid & 31, by = tid >> 5;    // 32x32 thread grid
  const int i0 = 3*bx, j0 = 3*by;            // each thread owns 3x3 nodes

  // Persistent sigma window: S[a][b] = sigma(cell i0-1+a, j0-1+b), 0 outside.
  float S[4][4];
  #pragma unroll
  for (int a = 0; a < 4; a++)
    #pragma unroll
    for (int b = 0; b < 4; b++){
      int ci = i0-1+a, cj = j0-1+b;
      float m = 0.f;
      if (ci >= 0 && ci < NCW && cj >= 0 && cj < NCW)
        m = 0.001f + 0.999f * mask[cj*NCW + ci];
      S[a][b] = m;
    }

  // Jacobi inverse-diagonal (0 on Dirichlet rows: i==0 or i==95)
  float invd[3][3];
  #pragma unroll
  for (int di = 0; di < 3; di++)
    #pragma unroll
    for (int dj = 0; dj < 3; dj++){
      float s00 = S[di+1][dj+1], sW = S[di][dj+1], sS = S[di+1][dj], sWS = S[di][dj];
      float cD = s00 + 3.f*sW + sS + sWS;
      bool isbc = (i0+di == 0) || (i0+di == NXN-1);
      invd[di][dj] = isbc ? 0.f : 1.f/cD;
    }

  // 7-point stencil apply on a 5x5 window (row i BC-masked)
  #define STENCIL(Wm, di, dj, dst)                                          \
    {                                                                        \
      int i_ = i0+(di);                                                      \
      bool isbc_ = (i_ == 0) || (i_ == NXN-1);                               \
      float s00 = S[(di)+1][(dj)+1], sW = S[(di)][(dj)+1];                   \
      float sS  = S[(di)+1][(dj)],   sWS = S[(di)][(dj)];                    \
      float v_ = (s00 + 3.f*sW + sS + sWS)*Wm[(di)+1][(dj)+1]                \
               + 0.5f*(sS - s00)*Wm[(di)+2][(dj)+1]                          \
               + 0.5f*(sWS - sW)*Wm[(di)][(dj)+1]                            \
               - 0.5f*(s00 + 3.f*sW)*Wm[(di)+1][(dj)+2]                      \
               - 0.5f*(sS + 3.f*sWS)*Wm[(di)+1][(dj)]                        \
               - sW*Wm[(di)][(dj)+2]                                         \
               - sS*Wm[(di)+2][(dj)];                                        \
      dst = isbc_ ? 0.f : v_;                                                \
    }

  // ---- init: warm start u0lin = 1 - i/95 (exact BC); r0 = -(A u0lin) ----
  float x[3][3], r[3][3], w[3][3], z[3][3], s[3][3], p[3][3];
  #pragma unroll
  for (int di = 0; di < 3; di++)
    #pragma unroll
    for (int dj = 0; dj < 3; dj++){
      x[di][dj] = 0.f; z[di][dj] = 0.f; s[di][dj] = 0.f; p[di][dj] = 0.f;
      int i = i0+di;
      float s00 = S[di+1][dj+1], sW = S[di][dj+1], sS = S[di+1][dj], sWS = S[di][dj];
      float uc = 1.f - (float)i     * (1.f/95.f);
      float uE = 1.f - (float)(i+1) * (1.f/95.f);
      float uW = 1.f - (float)(i-1) * (1.f/95.f);
      float v = (s00 + 3.f*sW + sS + sWS)*uc
              + 0.5f*(sS - s00)*uE
              + 0.5f*(sWS - sW)*uW
              - 0.5f*(s00 + 3.f*sW)*uc
              - 0.5f*(sS + 3.f*sWS)*uc
              - sW*uW
              - sS*uE;
      bool isbc = (i == 0) || (i == NXN-1);
      float rv = isbc ? 0.f : -v;
      r[di][dj] = rv;
      float uv = rv * invd[di][dj];            // u0 = M r0
      s_buf1[(j0+dj)*NXN + i] = uv;            // publish u0 (buf1)
    }
  __syncthreads();

  // w0 = A u0
  {
    float Wm[5][5];
    #pragma unroll
    for (int a = 0; a < 5; a++)
      #pragma unroll
      for (int b = 0; b < 5; b++){
        int gi = i0-1+a, gj = j0-1+b;
        Wm[a][b] = (gi >= 0 && gi < NXN && gj >= 0 && gj < NXN) ? s_buf1[gj*NXN + gi] : 0.f;
      }
    #pragma unroll
    for (int di = 0; di < 3; di++)
      #pragma unroll
      for (int dj = 0; dj < 3; dj++)
        STENCIL(Wm, di, dj, w[di][dj]);
  }

  double gamma_old = 1.0, alpha_old = 1.0, tol = 0.0;
  double gmin = 1e300; int since_min = 0;

  // ---- pipelined PCG (Ghysels-Vanroose): ONE barrier per iteration ----
  for (int it = 0; it < MAXIT; ++it){
    float* pub = (it & 1) ? s_buf1 : s_buf0;

    // m = M w ; publish; local dots gamma=r.u, delta=w.u (u = invd*r)
    float m[3][3];
    double gp = 0.0, dp = 0.0;
    #pragma unroll
    for (int di = 0; di < 3; di++)
      #pragma unroll
      for (int dj = 0; dj < 3; dj++){
        float mv = invd[di][dj] * w[di][dj];
        m[di][dj] = mv;
        pub[(j0+dj)*NXN + (i0+di)] = mv;
        double uv = (double)(invd[di][dj] * r[di][dj]);
        gp += (double)r[di][dj] * uv;
        dp += (double)w[di][dj] * uv;
      }
    dual_warp_red(gp, dp);
    if (lane == 0){ s_gA[it&1][wid] = gp; s_gB[it&1][wid] = dp; }
    __syncthreads();                       // publishes m AND partials

    // matvec n = A m (halo from pub) — overlaps the sum16 below via ILP
    float n[3][3];
    {
      float Wm[5][5];
      #pragma unroll
      for (int a = 0; a < 5; a++)
        #pragma unroll
        for (int b = 0; b < 5; b++){
          if (a >= 1 && a <= 3 && b >= 1 && b <= 3){ Wm[a][b] = m[a-1][b-1]; continue; }
          int gi = i0-1+a, gj = j0-1+b;
          Wm[a][b] = (gi >= 0 && gi < NXN && gj >= 0 && gj < NXN) ? pub[gj*NXN + gi] : 0.f;
        }
      #pragma unroll
      for (int di = 0; di < 3; di++)
        #pragma unroll
        for (int dj = 0; dj < 3; dj++)
          STENCIL(Wm, di, dj, n[di][dj]);
    }

    double gamma = sum16_tree(s_gA[it&1]);
    double delta = sum16_tree(s_gB[it&1]);
    if (it == 0) tol = gamma * TOL_REL;
    if (gamma <= tol || !(delta > 0.0)) break;   // uniform across waves

    // fp32 pipelined-CG drift floor: break when gamma stops making progress.
    // (uniform: gamma is identical across all threads)
    if (gamma < gmin * 0.999){ gmin = gamma; since_min = 0; }
    else if (++since_min >= STALL_WIN) break;

    double beta  = (it == 0) ? 0.0 : gamma / gamma_old;
    double alpha = (it == 0) ? gamma / delta
                             : gamma / (delta - beta * gamma / alpha_old);
    gamma_old = gamma; alpha_old = alpha;
    float bf = (float)beta, af = (float)alpha;

    #pragma unroll
    for (int di = 0; di < 3; di++)
      #pragma unroll
      for (int dj = 0; dj < 3; dj++){
        float zn = n[di][dj] + bf * z[di][dj];  z[di][dj] = zn;   // z = A(M s)
        float sn = w[di][dj] + bf * s[di][dj];  s[di][dj] = sn;   // s = A p
        float uv = invd[di][dj] * r[di][dj];
        float pn = uv + bf * p[di][dj];         p[di][dj] = pn;
        x[di][dj] += af * pn;
        r[di][dj] -= af * sn;
        w[di][dj] -= af * zn;
      }
  }

  __syncthreads();   // all waves done with pub buffers before final publish

  // ---- final u = u0lin + x into s_buf0 ----
  #pragma unroll
  for (int di = 0; di < 3; di++)
    #pragma unroll
    for (int dj = 0; dj < 3; dj++){
      int i = i0+di, j = j0+dj;
      float u;
      if (i == 0) u = 1.f;
      else if (i == NXN-1) u = 0.f;
      else u = 1.f - (float)i*(1.f/95.f) + x[di][dj];
      s_buf0[j*NXN + i] = u;
    }
  __syncthreads();

  // ---- energy: per cell sigma*0.5*(|gradA|^2 + |gradB|^2) ----
  float U[4][4];
  #pragma unroll
  for (int a = 0; a < 4; a++)
    #pragma unroll
    for (int b = 0; b < 4; b++){
      int gi = i0+a, gj = j0+b;
      U[a][b] = (gi < NXN && gj < NXN) ? s_buf0[gj*NXN + gi] : 0.f;
    }
  double ep = 0.0;
  #pragma unroll
  for (int di = 0; di < 3; di++)
    #pragma unroll
    for (int dj = 0; dj < 3; dj++){
      int ci = i0+di, cj = j0+dj;
      if (ci < NCW && cj < NCW){
        float sig = S[di+1][dj+1];
        float u00 = U[di][dj], uE = U[di+1][dj], uN = U[di][dj+1], uNE = U[di+1][dj+1];
        float gxA = uE - u00, gyA = uN - u00;
        float gxB = -2.f*uE + uNE + uN, gyB = uE - uNE;
        ep += (double)(sig * 0.5f * (gxA*gxA + gyA*gyA + gxB*gxB + gyB*gyB));
      }
    }
  {
    double dummy = 0.0;
    dual_warp_red(ep, dummy);
    if (lane == 0) s_gA[0][wid] = ep;
  }
  __syncthreads();
  if (tid == 0) out[0] = (float)sum16_tree(s_gA[0]);
}

extern "C" void kernel_launch(void* const* d_in, const int* in_sizes, int n_in,
                              void* d_out, int out_size, void* d_ws, size_t ws_size,
                              hipStream_t stream){
  (void)d_ws; (void)ws_size; (void)out_size;
  int mi = 0;
  for (int k = 0; k < n_in; k++) if (in_sizes[k] == 9025) { mi = k; break; }
  const float* mask = (const float*)d_in[mi];
  fem_cg_kernel<<<dim3(1), dim3(NTHREADS), 0, stream>>>(mask, (float*)d_out);
}

// Round 6
// 817.700 us; speedup vs baseline: 3.9755x; 3.9755x over previous
//
#include <hip/hip_runtime.h>

#define NXN 96
#define NNODE (NXN*NXN)
#define NCW 95
#define NTHREADS 1024
#define NWAVES (NTHREADS/64)
#define MAXIT_OUT 300
#define TOL_REL 1e-5
#define OMEGA 0.6f
#define NCOARSE_IT 8

__device__ __forceinline__ void dual_warp_red(double& a, double& b){
  #pragma unroll
  for (int off = 32; off > 0; off >>= 1){
    a += __shfl_down(a, off, 64);
    b += __shfl_down(b, off, 64);
  }
}

__device__ __forceinline__ double sum16_tree(const double* buf){
  double t0 = buf[0]  + buf[1],  t1 = buf[2]  + buf[3];
  double t2 = buf[4]  + buf[5],  t3 = buf[6]  + buf[7];
  double t4 = buf[8]  + buf[9],  t5 = buf[10] + buf[11];
  double t6 = buf[12] + buf[13], t7 = buf[14] + buf[15];
  double u0 = t0 + t1, u1 = t2 + t3, u2 = t4 + t5, u3 = t6 + t7;
  return (u0 + u1) + (u2 + u3);
}

// ---- generic level helpers (coarse levels: Dirichlet at i==0 only) ----
template<int N, int NC>
__device__ __forceinline__ float sgf(const float* sig, int ci, int cj){
  return (ci >= 0 && ci < NC && cj >= 0 && cj < NC) ? sig[cj*NC + ci] : 0.f;
}
template<int N>
__device__ __forceinline__ float vf(const float* v, int i, int j){
  return (i >= 0 && i < N && j >= 0 && j < N) ? v[j*N + i] : 0.f;
}
template<int N, int NC>
__device__ __forceinline__ float diagA(const float* sig, int i, int j){
  float s00 = sgf<N,NC>(sig,i,j),   sW  = sgf<N,NC>(sig,i-1,j);
  float sS  = sgf<N,NC>(sig,i,j-1), sWS = sgf<N,NC>(sig,i-1,j-1);
  return s00 + 3.f*sW + sS + sWS;
}
template<int N, int NC>
__device__ __forceinline__ float applyA(const float* sig, const float* v, int i, int j){
  float s00 = sgf<N,NC>(sig,i,j),   sW  = sgf<N,NC>(sig,i-1,j);
  float sS  = sgf<N,NC>(sig,i,j-1), sWS = sgf<N,NC>(sig,i-1,j-1);
  return (s00 + 3.f*sW + sS + sWS)*vf<N>(v,i,j)
       + 0.5f*(sS  - s00)*vf<N>(v,i+1,j)
       + 0.5f*(sWS - sW )*vf<N>(v,i-1,j)
       - 0.5f*(s00 + 3.f*sW )*vf<N>(v,i,j+1)
       - 0.5f*(sS  + 3.f*sWS)*vf<N>(v,i,j-1)
       - sW*vf<N>(v,i-1,j+1)
       - sS*vf<N>(v,i+1,j-1);
}
template<int N, int NC>
__device__ void smooth_from_zero(const float* sig, const float* f, float* z, int tid){
  for (int n = tid; n < N*N; n += NTHREADS){
    int i = n % N, j = n / N;
    z[n] = (i == 0) ? 0.f : OMEGA * f[n] / diagA<N,NC>(sig,i,j);
  }
}
template<int N, int NC>
__device__ void residual_lvl(const float* sig, const float* f, const float* z, float* dout, int tid){
  for (int n = tid; n < N*N; n += NTHREADS){
    int i = n % N, j = n / N;
    dout[n] = (i == 0) ? 0.f : f[n] - applyA<N,NC>(sig,z,i,j);
  }
}
template<int Nf, int Nc>
__device__ void restrict_to(const float* dfine, float* fc, int tid){
  for (int n = tid; n < Nc*Nc; n += NTHREADS){
    int I = n % Nc, J = n / Nc;
    float v = 0.f;
    if (I != 0){
      int fi = 2*I, fj = 2*J;
      v = vf<Nf>(dfine,fi,fj)
        + 0.5f*( vf<Nf>(dfine,fi+1,fj) + vf<Nf>(dfine,fi-1,fj)
               + vf<Nf>(dfine,fi,fj+1) + vf<Nf>(dfine,fi,fj-1)
               + vf<Nf>(dfine,fi+1,fj-1) + vf<Nf>(dfine,fi-1,fj+1) );
    }
    fc[n] = v;
  }
}
template<int Nf, int Nc>
__device__ void prolong_add(const float* zc, float* zfine, int tid){
  for (int n = tid; n < Nf*Nf; n += NTHREADS){
    int i = n % Nf, j = n / Nf;
    if (i == 0) continue;
    int ie = i & 1, je = j & 1;
    float add;
    if (!ie && !je)      add = vf<Nc>(zc, i>>1, j>>1);
    else if (ie && !je)  add = 0.5f*(vf<Nc>(zc,(i-1)>>1, j>>1) + vf<Nc>(zc,(i+1)>>1, j>>1));
    else if (!ie && je)  add = 0.5f*(vf<Nc>(zc, i>>1, (j-1)>>1) + vf<Nc>(zc, i>>1, (j+1)>>1));
    else                 add = 0.5f*(vf<Nc>(zc,(i+1)>>1,(j-1)>>1) + vf<Nc>(zc,(i-1)>>1,(j+1)>>1));
    zfine[n] += add;
  }
}
template<int N, int NC, int MAXOWN>
__device__ void post_smooth(const float* sig, const float* f, float* z, int tid){
  float nv[MAXOWN];
  int k = 0;
  #pragma unroll
  for (int n = tid; n < N*N; n += NTHREADS, ++k){
    int i = n % N, j = n / N;
    nv[k] = (i == 0) ? 0.f
          : z[n] + OMEGA * (f[n] - applyA<N,NC>(sig,z,i,j)) / diagA<N,NC>(sig,i,j);
  }
  __syncthreads();
  k = 0;
  #pragma unroll
  for (int n = tid; n < N*N; n += NTHREADS, ++k) z[n] = nv[k];
  __syncthreads();
}

__global__ __launch_bounds__(NTHREADS, 1)
void fem_mgcg_kernel(const float* __restrict__ mask, float* __restrict__ out){
  __shared__ float bufA[NNODE];          // fine z publish
  __shared__ float bufB[NNODE];          // fine residual d0 / final u
  __shared__ float z1[48*48], f1[48*48];
  __shared__ float z2[24*24], f2[24*24];
  __shared__ float z3[12*12], f3[12*12];
  __shared__ float z4a[6*6], z4b[6*6], f4[6*6];
  __shared__ float sc1[47*47], sc2[23*23], sc3[11*11], sc4[5*5];
  __shared__ float dscratch[48*48];
  __shared__ double pA[NWAVES], pB[NWAVES];

  const int tid = threadIdx.x, lane = tid & 63, wid = tid >> 6;
  const int bx = tid & 31, by = tid >> 5;
  const int i0 = 3*bx, j0 = 3*by;

  // ---- setup: fine sigma window in registers ----
  float S[4][4];
  #pragma unroll
  for (int a = 0; a < 4; a++)
    #pragma unroll
    for (int b = 0; b < 4; b++){
      int ci = i0-1+a, cj = j0-1+b;
      float m = 0.f;
      if (ci >= 0 && ci < NCW && cj >= 0 && cj < NCW)
        m = 0.001f + 0.999f * mask[cj*NCW + ci];
      S[a][b] = m;
    }
  float invd[3][3];
  #pragma unroll
  for (int di = 0; di < 3; di++)
    #pragma unroll
    for (int dj = 0; dj < 3; dj++){
      float cD = S[di+1][dj+1] + 3.f*S[di][dj+1] + S[di+1][dj] + S[di][dj];
      bool isbc = (i0+di == 0) || (i0+di == NXN-1);
      invd[di][dj] = isbc ? 0.f : 1.f/cD;
    }

  // ---- setup: coarse sigma hierarchies (4-cell averaging) ----
  for (int n = tid; n < 47*47; n += NTHREADS){
    int CI = n % 47, CJ = n / 47;
    float acc = 0.f;
    #pragma unroll
    for (int b = 0; b < 2; b++)
      #pragma unroll
      for (int a = 0; a < 2; a++)
        acc += 0.001f + 0.999f * mask[(2*CJ+b)*NCW + (2*CI+a)];
    sc1[n] = 0.25f * acc;
  }
  __syncthreads();
  for (int n = tid; n < 23*23; n += NTHREADS){
    int CI = n % 23, CJ = n / 23;
    sc2[n] = 0.25f*(sc1[(2*CJ)*47+2*CI]   + sc1[(2*CJ)*47+2*CI+1]
                  + sc1[(2*CJ+1)*47+2*CI] + sc1[(2*CJ+1)*47+2*CI+1]);
  }
  __syncthreads();
  for (int n = tid; n < 11*11; n += NTHREADS){
    int CI = n % 11, CJ = n / 11;
    sc3[n] = 0.25f*(sc2[(2*CJ)*23+2*CI]   + sc2[(2*CJ)*23+2*CI+1]
                  + sc2[(2*CJ+1)*23+2*CI] + sc2[(2*CJ+1)*23+2*CI+1]);
  }
  __syncthreads();
  for (int n = tid; n < 5*5; n += NTHREADS){
    int CI = n % 5, CJ = n / 5;
    sc4[n] = 0.25f*(sc3[(2*CJ)*11+2*CI]   + sc3[(2*CJ)*11+2*CI+1]
                  + sc3[(2*CJ+1)*11+2*CI] + sc3[(2*CJ+1)*11+2*CI+1]);
  }
  __syncthreads();

  // fine stencil on a 5x5 register window (rows i==0,95 masked)
  #define STENCIL(Wm, di, dj, dst)                                          \
    {                                                                        \
      int i_ = i0+(di);                                                      \
      bool isbc_ = (i_ == 0) || (i_ == NXN-1);                               \
      float s00 = S[(di)+1][(dj)+1], sW = S[(di)][(dj)+1];                   \
      float sS  = S[(di)+1][(dj)],   sWS = S[(di)][(dj)];                    \
      float v_ = (s00 + 3.f*sW + sS + sWS)*Wm[(di)+1][(dj)+1]                \
               + 0.5f*(sS - s00)*Wm[(di)+2][(dj)+1]                          \
               + 0.5f*(sWS - sW)*Wm[(di)][(dj)+1]                            \
               - 0.5f*(s00 + 3.f*sW)*Wm[(di)+1][(dj)+2]                      \
               - 0.5f*(sS + 3.f*sWS)*Wm[(di)+1][(dj)]                        \
               - sW*Wm[(di)][(dj)+2]                                         \
               - sS*Wm[(di)+2][(dj)];                                        \
      dst = isbc_ ? 0.f : v_;                                                \
    }

  #define GATHER5x5(Wm, own, buf)                                           \
    _Pragma("unroll")                                                        \
    for (int a = 0; a < 5; a++)                                              \
      _Pragma("unroll")                                                      \
      for (int b = 0; b < 5; b++){                                           \
        if (a >= 1 && a <= 3 && b >= 1 && b <= 3){ Wm[a][b] = own[a-1][b-1]; continue; } \
        int gi = i0-1+a, gj = j0-1+b;                                        \
        Wm[a][b] = (gi >= 0 && gi < NXN && gj >= 0 && gj < NXN) ? buf[gj*NXN + gi] : 0.f; \
      }

  // ---- warm start u0lin = 1 - i/95 ; r0 = -(A u0lin) on free rows ----
  float x[3][3], r[3][3], z0[3][3], w[3][3], p[3][3], s[3][3];
  #pragma unroll
  for (int di = 0; di < 3; di++)
    #pragma unroll
    for (int dj = 0; dj < 3; dj++){
      x[di][dj] = 0.f; p[di][dj] = 0.f; s[di][dj] = 0.f;
      int i = i0+di;
      float s00 = S[di+1][dj+1], sW = S[di][dj+1], sS = S[di+1][dj], sWS = S[di][dj];
      float uc = 1.f - (float)i     * (1.f/95.f);
      float uE = 1.f - (float)(i+1) * (1.f/95.f);
      float uW = 1.f - (float)(i-1) * (1.f/95.f);
      float v = (s00 + 3.f*sW + sS + sWS)*uc
              + 0.5f*(sS - s00)*uE + 0.5f*(sWS - sW)*uW
              - 0.5f*(s00 + 3.f*sW)*uc - 0.5f*(sS + 3.f*sWS)*uc
              - sW*uW - sS*uE;
      bool isbc = (i == 0) || (i == NXN-1);
      r[di][dj] = isbc ? 0.f : -v;
    }

  double gamma_old = 1.0, alpha_old = 1.0, tol = 0.0;

  // ======== outer PCG (Chronopoulos-Gear) with MG V-cycle preconditioner ====
  for (int it = 0; it < MAXIT_OUT; ++it){
    // ---- V-cycle: z0 = M^{-1} r ----
    // L0 pre-smooth + publish
    #pragma unroll
    for (int di = 0; di < 3; di++)
      #pragma unroll
      for (int dj = 0; dj < 3; dj++){
        float zv = OMEGA * invd[di][dj] * r[di][dj];
        z0[di][dj] = zv;
        bufA[(j0+dj)*NXN + (i0+di)] = zv;
      }
    __syncthreads();
    // L0 residual -> bufB
    {
      float Wm[5][5];
      GATHER5x5(Wm, z0, bufA);
      #pragma unroll
      for (int di = 0; di < 3; di++)
        #pragma unroll
        for (int dj = 0; dj < 3; dj++){
          float av; STENCIL(Wm, di, dj, av);
          int i = i0+di;
          bool isbc = (i == 0) || (i == NXN-1);
          bufB[(j0+dj)*NXN + i] = isbc ? 0.f : (r[di][dj] - av);
        }
    }
    __syncthreads();
    restrict_to<96,48>(bufB, f1, tid);               __syncthreads();
    smooth_from_zero<48,47>(sc1, f1, z1, tid);       __syncthreads();
    residual_lvl<48,47>(sc1, f1, z1, dscratch, tid); __syncthreads();
    restrict_to<48,24>(dscratch, f2, tid);           __syncthreads();
    smooth_from_zero<24,23>(sc2, f2, z2, tid);       __syncthreads();
    residual_lvl<24,23>(sc2, f2, z2, dscratch, tid); __syncthreads();
    restrict_to<24,12>(dscratch, f3, tid);           __syncthreads();
    smooth_from_zero<12,11>(sc3, f3, z3, tid);       __syncthreads();
    residual_lvl<12,11>(sc3, f3, z3, dscratch, tid); __syncthreads();
    restrict_to<12,6>(dscratch, f4, tid);            __syncthreads();
    // L4 coarse solve: 8 damped-Jacobi sweeps (double-buffered)
    smooth_from_zero<6,5>(sc4, f4, z4a, tid);        __syncthreads();
    float* zc;
    {
      float* cur = z4a; float* nxt = z4b;
      for (int k = 1; k < NCOARSE_IT; ++k){
        for (int n = tid; n < 36; n += NTHREADS){
          int i = n % 6, j = n / 6;
          nxt[n] = (i == 0) ? 0.f
                 : cur[n] + OMEGA * (f4[n] - applyA<6,5>(sc4,cur,i,j)) / diagA<6,5>(sc4,i,j);
        }
        __syncthreads();
        float* t = cur; cur = nxt; nxt = t;
      }
      zc = cur;
    }
    prolong_add<12,6>(zc, z3, tid);  __syncthreads();
    post_smooth<12,11,1>(sc3, f3, z3, tid);
    prolong_add<24,12>(z3, z2, tid); __syncthreads();
    post_smooth<24,23,1>(sc2, f2, z2, tid);
    prolong_add<48,24>(z2, z1, tid); __syncthreads();
    post_smooth<48,47,3>(sc1, f1, z1, tid);
    // L0 prolong into registers (mask BC rows)
    #pragma unroll
    for (int di = 0; di < 3; di++)
      #pragma unroll
      for (int dj = 0; dj < 3; dj++){
        int i = i0+di, j = j0+dj;
        if (i == 0 || i == NXN-1) continue;
        int ie = i & 1, je = j & 1;
        float add;
        if (!ie && !je)      add = vf<48>(z1, i>>1, j>>1);
        else if (ie && !je)  add = 0.5f*(vf<48>(z1,(i-1)>>1, j>>1) + vf<48>(z1,(i+1)>>1, j>>1));
        else if (!ie && je)  add = 0.5f*(vf<48>(z1, i>>1, (j-1)>>1) + vf<48>(z1, i>>1, (j+1)>>1));
        else                 add = 0.5f*(vf<48>(z1,(i+1)>>1,(j-1)>>1) + vf<48>(z1,(i-1)>>1,(j+1)>>1));
        z0[di][dj] += add;
      }
    // publish, post-smooth L0
    #pragma unroll
    for (int di = 0; di < 3; di++)
      #pragma unroll
      for (int dj = 0; dj < 3; dj++)
        bufA[(j0+dj)*NXN + (i0+di)] = z0[di][dj];
    __syncthreads();
    {
      float Wm[5][5];
      GATHER5x5(Wm, z0, bufA);
      #pragma unroll
      for (int di = 0; di < 3; di++)
        #pragma unroll
        for (int dj = 0; dj < 3; dj++){
          float av; STENCIL(Wm, di, dj, av);
          z0[di][dj] += OMEGA * invd[di][dj] * (r[di][dj] - av);
        }
    }
    __syncthreads();   // all reads of bufA done before republish
    #pragma unroll
    for (int di = 0; di < 3; di++)
      #pragma unroll
      for (int dj = 0; dj < 3; dj++)
        bufA[(j0+dj)*NXN + (i0+di)] = z0[di][dj];
    __syncthreads();

    // ---- outer matvec w = A z ; dots gamma = r.z, delta = w.z ----
    double gp = 0.0, dp = 0.0;
    {
      float Wm[5][5];
      GATHER5x5(Wm, z0, bufA);
      #pragma unroll
      for (int di = 0; di < 3; di++)
        #pragma unroll
        for (int dj = 0; dj < 3; dj++){
          float av; STENCIL(Wm, di, dj, av);
          w[di][dj] = av;
          gp += (double)r[di][dj] * (double)z0[di][dj];
          dp += (double)av        * (double)z0[di][dj];
        }
    }
    dual_warp_red(gp, dp);
    if (lane == 0){ pA[wid] = gp; pB[wid] = dp; }
    __syncthreads();
    double gamma = sum16_tree(pA);
    double delta = sum16_tree(pB);
    if (it == 0) tol = gamma * TOL_REL;
    if (gamma <= tol || !(delta > 0.0)) break;

    double beta  = (it == 0) ? 0.0 : gamma / gamma_old;
    double alpha = (it == 0) ? gamma / delta
                             : gamma / (delta - beta * gamma / alpha_old);
    gamma_old = gamma; alpha_old = alpha;
    float bf = (float)beta, af = (float)alpha;

    #pragma unroll
    for (int di = 0; di < 3; di++)
      #pragma unroll
      for (int dj = 0; dj < 3; dj++){
        float pn = z0[di][dj] + bf * p[di][dj];  p[di][dj] = pn;
        float sn = w[di][dj]  + bf * s[di][dj];  s[di][dj] = sn;
        x[di][dj] += af * pn;
        r[di][dj] -= af * sn;
      }
  }

  // ---- final u = u0lin + x into bufB ----
  #pragma unroll
  for (int di = 0; di < 3; di++)
    #pragma unroll
    for (int dj = 0; dj < 3; dj++){
      int i = i0+di, j = j0+dj;
      float u;
      if (i == 0) u = 1.f;
      else if (i == NXN-1) u = 0.f;
      else u = 1.f - (float)i*(1.f/95.f) + x[di][dj];
      bufB[j*NXN + i] = u;
    }
  __syncthreads();

  // ---- energy ----
  float U[4][4];
  #pragma unroll
  for (int a = 0; a < 4; a++)
    #pragma unroll
    for (int b = 0; b < 4; b++){
      int gi = i0+a, gj = j0+b;
      U[a][b] = (gi < NXN && gj < NXN) ? bufB[gj*NXN + gi] : 0.f;
    }
  double ep = 0.0;
  #pragma unroll
  for (int di = 0; di < 3; di++)
    #pragma unroll
    for (int dj = 0; dj < 3; dj++){
      int ci = i0+di, cj = j0+dj;
      if (ci < NCW && cj < NCW){
        float sig = S[di+1][dj+1];
        float u00 = U[di][dj], uE = U[di+1][dj], uN = U[di][dj+1], uNE = U[di+1][dj+1];
        float gxA = uE - u00, gyA = uN - u00;
        float gxB = -2.f*uE + uNE + uN, gyB = uE - uNE;
        ep += (double)(sig * 0.5f * (gxA*gxA + gyA*gyA + gxB*gxB + gyB*gyB));
      }
    }
  {
    double dummy = 0.0;
    dual_warp_red(ep, dummy);
    if (lane == 0) pA[wid] = ep;
  }
  __syncthreads();
  if (tid == 0) out[0] = (float)sum16_tree(pA);
}

extern "C" void kernel_launch(void* const* d_in, const int* in_sizes, int n_in,
                              void* d_out, int out_size, void* d_ws, size_t ws_size,
                              hipStream_t stream){
  (void)d_ws; (void)ws_size; (void)out_size;
  int mi = 0;
  for (int k = 0; k < n_in; k++) if (in_sizes[k] == 9025) { mi = k; break; }
  const float* mask = (const float*)d_in[mi];
  fem_mgcg_kernel<<<dim3(1), dim3(NTHREADS), 0, stream>>>(mask, (float*)d_out);
}

// Round 7
// 402.688 us; speedup vs baseline: 8.0726x; 2.0306x over previous
//
#include <hip/hip_runtime.h>

#define NXN 96
#define NNODE (NXN*NXN)
#define NCW 95
#define NTHREADS 1024
#define NWAVES (NTHREADS/64)
#define MAXIT_OUT 300
#define ATOL_E 3e-4       // absolute bound on alpha*gamma (energy-error tail)
#define OMEGA 0.6f
#define NCOARSE_IT 8

__device__ __forceinline__ void dual_warp_red(double& a, double& b){
  #pragma unroll
  for (int off = 32; off > 0; off >>= 1){
    a += __shfl_down(a, off, 64);
    b += __shfl_down(b, off, 64);
  }
}

__device__ __forceinline__ double sum16_tree(const double* buf){
  double t0 = buf[0]  + buf[1],  t1 = buf[2]  + buf[3];
  double t2 = buf[4]  + buf[5],  t3 = buf[6]  + buf[7];
  double t4 = buf[8]  + buf[9],  t5 = buf[10] + buf[11];
  double t6 = buf[12] + buf[13], t7 = buf[14] + buf[15];
  double u0 = t0 + t1, u1 = t2 + t3, u2 = t4 + t5, u3 = t6 + t7;
  return (u0 + u1) + (u2 + u3);
}

// ---- generic level helpers (coarse levels: Dirichlet at i==0 only) ----
template<int N, int NC>
__device__ __forceinline__ float sgf(const float* sig, int ci, int cj){
  return (ci >= 0 && ci < NC && cj >= 0 && cj < NC) ? sig[cj*NC + ci] : 0.f;
}
template<int N>
__device__ __forceinline__ float vf(const float* v, int i, int j){
  return (i >= 0 && i < N && j >= 0 && j < N) ? v[j*N + i] : 0.f;
}
template<int N, int NC>
__device__ __forceinline__ float diagA(const float* sig, int i, int j){
  float s00 = sgf<N,NC>(sig,i,j),   sW  = sgf<N,NC>(sig,i-1,j);
  float sS  = sgf<N,NC>(sig,i,j-1), sWS = sgf<N,NC>(sig,i-1,j-1);
  return s00 + 3.f*sW + sS + sWS;
}
template<int N, int NC>
__device__ __forceinline__ float applyA(const float* sig, const float* v, int i, int j){
  float s00 = sgf<N,NC>(sig,i,j),   sW  = sgf<N,NC>(sig,i-1,j);
  float sS  = sgf<N,NC>(sig,i,j-1), sWS = sgf<N,NC>(sig,i-1,j-1);
  return (s00 + 3.f*sW + sS + sWS)*vf<N>(v,i,j)
       + 0.5f*(sS  - s00)*vf<N>(v,i+1,j)
       + 0.5f*(sWS - sW )*vf<N>(v,i-1,j)
       - 0.5f*(s00 + 3.f*sW )*vf<N>(v,i,j+1)
       - 0.5f*(sS  + 3.f*sWS)*vf<N>(v,i,j-1)
       - sW*vf<N>(v,i-1,j+1)
       - sS*vf<N>(v,i+1,j-1);
}
template<int N, int NC>
__device__ void smooth_from_zero(const float* sig, const float* f, float* z, int tid){
  for (int n = tid; n < N*N; n += NTHREADS){
    int i = n % N, j = n / N;
    z[n] = (i == 0) ? 0.f : OMEGA * f[n] / diagA<N,NC>(sig,i,j);
  }
}
template<int N, int NC>
__device__ void residual_lvl(const float* sig, const float* f, const float* z, float* dout, int tid){
  for (int n = tid; n < N*N; n += NTHREADS){
    int i = n % N, j = n / N;
    dout[n] = (i == 0) ? 0.f : f[n] - applyA<N,NC>(sig,z,i,j);
  }
}
template<int Nf, int Nc>
__device__ void restrict_to(const float* dfine, float* fc, int tid){
  for (int n = tid; n < Nc*Nc; n += NTHREADS){
    int I = n % Nc, J = n / Nc;
    float v = 0.f;
    if (I != 0){
      int fi = 2*I, fj = 2*J;
      v = vf<Nf>(dfine,fi,fj)
        + 0.5f*( vf<Nf>(dfine,fi+1,fj) + vf<Nf>(dfine,fi-1,fj)
               + vf<Nf>(dfine,fi,fj+1) + vf<Nf>(dfine,fi,fj-1)
               + vf<Nf>(dfine,fi+1,fj-1) + vf<Nf>(dfine,fi-1,fj+1) );
    }
    fc[n] = v;
  }
}
template<int Nf, int Nc>
__device__ void prolong_add(const float* zc, float* zfine, int tid){
  for (int n = tid; n < Nf*Nf; n += NTHREADS){
    int i = n % Nf, j = n / Nf;
    if (i == 0) continue;
    int ie = i & 1, je = j & 1;
    float add;
    if (!ie && !je)      add = vf<Nc>(zc, i>>1, j>>1);
    else if (ie && !je)  add = 0.5f*(vf<Nc>(zc,(i-1)>>1, j>>1) + vf<Nc>(zc,(i+1)>>1, j>>1));
    else if (!ie && je)  add = 0.5f*(vf<Nc>(zc, i>>1, (j-1)>>1) + vf<Nc>(zc, i>>1, (j+1)>>1));
    else                 add = 0.5f*(vf<Nc>(zc,(i+1)>>1,(j-1)>>1) + vf<Nc>(zc,(i-1)>>1,(j+1)>>1));
    zfine[n] += add;
  }
}
// post-smooth, double-buffered: zout = zin + w*D^-1*(f - A zin); no internal barriers
template<int N, int NC>
__device__ void post_smooth_db(const float* sig, const float* f, const float* zin, float* zout, int tid){
  for (int n = tid; n < N*N; n += NTHREADS){
    int i = n % N, j = n / N;
    zout[n] = (i == 0) ? 0.f
            : zin[n] + OMEGA * (f[n] - applyA<N,NC>(sig,zin,i,j)) / diagA<N,NC>(sig,i,j);
  }
}

__global__ __launch_bounds__(NTHREADS, 1)
void fem_mgcg_kernel(const float* __restrict__ mask, float* __restrict__ out){
  __shared__ float bufA[NNODE];          // fine z publish
  __shared__ float bufB[NNODE];          // fine residual d0 / final u
  __shared__ float z1[48*48], f1[48*48], z1b[48*48];
  __shared__ float z2[24*24], f2[24*24], z2b[24*24];
  __shared__ float z3[12*12], f3[12*12], z3b[12*12];
  __shared__ float z4a[6*6], z4b[6*6], f4[6*6];
  __shared__ float sc1[47*47], sc2[23*23], sc3[11*11], sc4[5*5];
  __shared__ float dscratch[48*48];
  __shared__ double pA[NWAVES], pB[NWAVES];

  const int tid = threadIdx.x, lane = tid & 63, wid = tid >> 6;
  const int bx = tid & 31, by = tid >> 5;
  const int i0 = 3*bx, j0 = 3*by;

  // ---- setup: fine sigma window in registers ----
  float S[4][4];
  #pragma unroll
  for (int a = 0; a < 4; a++)
    #pragma unroll
    for (int b = 0; b < 4; b++){
      int ci = i0-1+a, cj = j0-1+b;
      float m = 0.f;
      if (ci >= 0 && ci < NCW && cj >= 0 && cj < NCW)
        m = 0.001f + 0.999f * mask[cj*NCW + ci];
      S[a][b] = m;
    }
  float invd[3][3];
  #pragma unroll
  for (int di = 0; di < 3; di++)
    #pragma unroll
    for (int dj = 0; dj < 3; dj++){
      float cD = S[di+1][dj+1] + 3.f*S[di][dj+1] + S[di+1][dj] + S[di][dj];
      bool isbc = (i0+di == 0) || (i0+di == NXN-1);
      invd[di][dj] = isbc ? 0.f : 1.f/cD;
    }

  // ---- setup: coarse sigma hierarchies (4-cell averaging) ----
  for (int n = tid; n < 47*47; n += NTHREADS){
    int CI = n % 47, CJ = n / 47;
    float acc = 0.f;
    #pragma unroll
    for (int b = 0; b < 2; b++)
      #pragma unroll
      for (int a = 0; a < 2; a++)
        acc += 0.001f + 0.999f * mask[(2*CJ+b)*NCW + (2*CI+a)];
    sc1[n] = 0.25f * acc;
  }
  __syncthreads();
  for (int n = tid; n < 23*23; n += NTHREADS){
    int CI = n % 23, CJ = n / 23;
    sc2[n] = 0.25f*(sc1[(2*CJ)*47+2*CI]   + sc1[(2*CJ)*47+2*CI+1]
                  + sc1[(2*CJ+1)*47+2*CI] + sc1[(2*CJ+1)*47+2*CI+1]);
  }
  __syncthreads();
  for (int n = tid; n < 11*11; n += NTHREADS){
    int CI = n % 11, CJ = n / 11;
    sc3[n] = 0.25f*(sc2[(2*CJ)*23+2*CI]   + sc2[(2*CJ)*23+2*CI+1]
                  + sc2[(2*CJ+1)*23+2*CI] + sc2[(2*CJ+1)*23+2*CI+1]);
  }
  __syncthreads();
  for (int n = tid; n < 5*5; n += NTHREADS){
    int CI = n % 5, CJ = n / 5;
    sc4[n] = 0.25f*(sc3[(2*CJ)*11+2*CI]   + sc3[(2*CJ)*11+2*CI+1]
                  + sc3[(2*CJ+1)*11+2*CI] + sc3[(2*CJ+1)*11+2*CI+1]);
  }
  __syncthreads();

  // fine stencil on a 5x5 register window (rows i==0,95 masked)
  #define STENCIL(Wm, di, dj, dst)                                          \
    {                                                                        \
      int i_ = i0+(di);                                                      \
      bool isbc_ = (i_ == 0) || (i_ == NXN-1);                               \
      float s00 = S[(di)+1][(dj)+1], sW = S[(di)][(dj)+1];                   \
      float sS  = S[(di)+1][(dj)],   sWS = S[(di)][(dj)];                    \
      float v_ = (s00 + 3.f*sW + sS + sWS)*Wm[(di)+1][(dj)+1]                \
               + 0.5f*(sS - s00)*Wm[(di)+2][(dj)+1]                          \
               + 0.5f*(sWS - sW)*Wm[(di)][(dj)+1]                            \
               - 0.5f*(s00 + 3.f*sW)*Wm[(di)+1][(dj)+2]                      \
               - 0.5f*(sS + 3.f*sWS)*Wm[(di)+1][(dj)]                        \
               - sW*Wm[(di)][(dj)+2]                                         \
               - sS*Wm[(di)+2][(dj)];                                        \
      dst = isbc_ ? 0.f : v_;                                                \
    }

  #define GATHER5x5(Wm, own, buf)                                           \
    _Pragma("unroll")                                                        \
    for (int a = 0; a < 5; a++)                                              \
      _Pragma("unroll")                                                      \
      for (int b = 0; b < 5; b++){                                           \
        if (a >= 1 && a <= 3 && b >= 1 && b <= 3){ Wm[a][b] = own[a-1][b-1]; continue; } \
        int gi = i0-1+a, gj = j0-1+b;                                        \
        Wm[a][b] = (gi >= 0 && gi < NXN && gj >= 0 && gj < NXN) ? buf[gj*NXN + gi] : 0.f; \
      }

  // ---- warm start u0lin = 1 - i/95 ; r0 = -(A u0lin) on free rows ----
  float x[3][3], r[3][3], z0[3][3], w[3][3], p[3][3], s[3][3];
  #pragma unroll
  for (int di = 0; di < 3; di++)
    #pragma unroll
    for (int dj = 0; dj < 3; dj++){
      x[di][dj] = 0.f; p[di][dj] = 0.f; s[di][dj] = 0.f;
      int i = i0+di;
      float s00 = S[di+1][dj+1], sW = S[di][dj+1], sS = S[di+1][dj], sWS = S[di][dj];
      float uc = 1.f - (float)i     * (1.f/95.f);
      float uE = 1.f - (float)(i+1) * (1.f/95.f);
      float uW = 1.f - (float)(i-1) * (1.f/95.f);
      float v = (s00 + 3.f*sW + sS + sWS)*uc
              + 0.5f*(sS - s00)*uE + 0.5f*(sWS - sW)*uW
              - 0.5f*(s00 + 3.f*sW)*uc - 0.5f*(sS + 3.f*sWS)*uc
              - sW*uW - sS*uE;
      bool isbc = (i == 0) || (i == NXN-1);
      r[di][dj] = isbc ? 0.f : -v;
    }

  double gamma_old = 1.0, alpha_old = 1.0, gamma0 = 0.0;

  // ======== outer PCG (Chronopoulos-Gear) with MG V-cycle preconditioner ====
  for (int it = 0; it < MAXIT_OUT; ++it){
    // ---- V-cycle: z0 = M^{-1} r ----
    // L0 pre-smooth + publish
    #pragma unroll
    for (int di = 0; di < 3; di++)
      #pragma unroll
      for (int dj = 0; dj < 3; dj++){
        float zv = OMEGA * invd[di][dj] * r[di][dj];
        z0[di][dj] = zv;
        bufA[(j0+dj)*NXN + (i0+di)] = zv;
      }
    __syncthreads();
    // L0 residual -> bufB
    {
      float Wm[5][5];
      GATHER5x5(Wm, z0, bufA);
      #pragma unroll
      for (int di = 0; di < 3; di++)
        #pragma unroll
        for (int dj = 0; dj < 3; dj++){
          float av; STENCIL(Wm, di, dj, av);
          int i = i0+di;
          bool isbc = (i == 0) || (i == NXN-1);
          bufB[(j0+dj)*NXN + i] = isbc ? 0.f : (r[di][dj] - av);
        }
    }
    __syncthreads();
    restrict_to<96,48>(bufB, f1, tid);               __syncthreads();
    smooth_from_zero<48,47>(sc1, f1, z1, tid);       __syncthreads();
    residual_lvl<48,47>(sc1, f1, z1, dscratch, tid); __syncthreads();
    restrict_to<48,24>(dscratch, f2, tid);           __syncthreads();
    smooth_from_zero<24,23>(sc2, f2, z2, tid);       __syncthreads();
    residual_lvl<24,23>(sc2, f2, z2, dscratch, tid); __syncthreads();
    restrict_to<24,12>(dscratch, f3, tid);           __syncthreads();
    smooth_from_zero<12,11>(sc3, f3, z3, tid);       __syncthreads();
    residual_lvl<12,11>(sc3, f3, z3, dscratch, tid); __syncthreads();
    restrict_to<12,6>(dscratch, f4, tid);            __syncthreads();
    // L4 coarse solve: damped-Jacobi sweeps (double-buffered)
    smooth_from_zero<6,5>(sc4, f4, z4a, tid);        __syncthreads();
    float* zc;
    {
      float* cur = z4a; float* nxt = z4b;
      for (int k = 1; k < NCOARSE_IT; ++k){
        for (int n = tid; n < 36; n += NTHREADS){
          int i = n % 6, j = n / 6;
          nxt[n] = (i == 0) ? 0.f
                 : cur[n] + OMEGA * (f4[n] - applyA<6,5>(sc4,cur,i,j)) / diagA<6,5>(sc4,i,j);
        }
        __syncthreads();
        float* t = cur; cur = nxt; nxt = t;
      }
      zc = cur;
    }
    // upward: prolong + double-buffered post-smooth (2 barriers/level)
    prolong_add<12,6>(zc, z3, tid);                  __syncthreads();
    post_smooth_db<12,11>(sc3, f3, z3, z3b, tid);    __syncthreads();
    prolong_add<24,12>(z3b, z2, tid);                __syncthreads();
    post_smooth_db<24,23>(sc2, f2, z2, z2b, tid);    __syncthreads();
    prolong_add<48,24>(z2b, z1, tid);                __syncthreads();
    post_smooth_db<48,47>(sc1, f1, z1, z1b, tid);    __syncthreads();
    // L0 prolong from z1b into registers (mask BC rows)
    #pragma unroll
    for (int di = 0; di < 3; di++)
      #pragma unroll
      for (int dj = 0; dj < 3; dj++){
        int i = i0+di, j = j0+dj;
        if (i == 0 || i == NXN-1) continue;
        int ie = i & 1, je = j & 1;
        float add;
        if (!ie && !je)      add = vf<48>(z1b, i>>1, j>>1);
        else if (ie && !je)  add = 0.5f*(vf<48>(z1b,(i-1)>>1, j>>1) + vf<48>(z1b,(i+1)>>1, j>>1));
        else if (!ie && je)  add = 0.5f*(vf<48>(z1b, i>>1, (j-1)>>1) + vf<48>(z1b, i>>1, (j+1)>>1));
        else                 add = 0.5f*(vf<48>(z1b,(i+1)>>1,(j-1)>>1) + vf<48>(z1b,(i-1)>>1,(j+1)>>1));
        z0[di][dj] += add;
      }
    // publish, post-smooth L0
    #pragma unroll
    for (int di = 0; di < 3; di++)
      #pragma unroll
      for (int dj = 0; dj < 3; dj++)
        bufA[(j0+dj)*NXN + (i0+di)] = z0[di][dj];
    __syncthreads();
    {
      float Wm[5][5];
      GATHER5x5(Wm, z0, bufA);
      #pragma unroll
      for (int di = 0; di < 3; di++)
        #pragma unroll
        for (int dj = 0; dj < 3; dj++){
          float av; STENCIL(Wm, di, dj, av);
          z0[di][dj] += OMEGA * invd[di][dj] * (r[di][dj] - av);
        }
    }
    __syncthreads();   // all reads of bufA done before republish
    #pragma unroll
    for (int di = 0; di < 3; di++)
      #pragma unroll
      for (int dj = 0; dj < 3; dj++)
        bufA[(j0+dj)*NXN + (i0+di)] = z0[di][dj];
    __syncthreads();

    // ---- outer matvec w = A z ; dots gamma = r.z, delta = w.z ----
    double gp = 0.0, dp = 0.0;
    {
      float Wm[5][5];
      GATHER5x5(Wm, z0, bufA);
      #pragma unroll
      for (int di = 0; di < 3; di++)
        #pragma unroll
        for (int dj = 0; dj < 3; dj++){
          float av; STENCIL(Wm, di, dj, av);
          w[di][dj] = av;
          gp += (double)r[di][dj] * (double)z0[di][dj];
          dp += (double)av        * (double)z0[di][dj];
        }
    }
    dual_warp_red(gp, dp);
    if (lane == 0){ pA[wid] = gp; pB[wid] = dp; }
    __syncthreads();
    double gamma = sum16_tree(pA);
    double delta = sum16_tree(pB);
    if (it == 0) gamma0 = gamma;
    if (gamma <= gamma0 * 1e-9 || !(delta > 0.0)) break;   // safety floor

    double beta  = (it == 0) ? 0.0 : gamma / gamma_old;
    double alpha = (it == 0) ? gamma / delta
                             : gamma / (delta - beta * gamma / alpha_old);
    gamma_old = gamma; alpha_old = alpha;
    float bf = (float)beta, af = (float)alpha;

    #pragma unroll
    for (int di = 0; di < 3; di++)
      #pragma unroll
      for (int dj = 0; dj < 3; dj++){
        float pn = z0[di][dj] + bf * p[di][dj];  p[di][dj] = pn;
        float sn = w[di][dj]  + bf * s[di][dj];  s[di][dj] = sn;
        x[di][dj] += af * pn;
        r[di][dj] -= af * sn;
      }

    // absolute energy-error tail bound: ||e||_A^2 after this update
    // ~ alpha*gamma * rho/(1-rho)  ->  stop when alpha*gamma small
    if (alpha * gamma <= ATOL_E) break;
  }

  // ---- final u = u0lin + x into bufB ----
  #pragma unroll
  for (int di = 0; di < 3; di++)
    #pragma unroll
    for (int dj = 0; dj < 3; dj++){
      int i = i0+di, j = j0+dj;
      float u;
      if (i == 0) u = 1.f;
      else if (i == NXN-1) u = 0.f;
      else u = 1.f - (float)i*(1.f/95.f) + x[di][dj];
      bufB[j*NXN + i] = u;
    }
  __syncthreads();

  // ---- energy ----
  float U[4][4];
  #pragma unroll
  for (int a = 0; a < 4; a++)
    #pragma unroll
    for (int b = 0; b < 4; b++){
      int gi = i0+a, gj = j0+b;
      U[a][b] = (gi < NXN && gj < NXN) ? bufB[gj*NXN + gi] : 0.f;
    }
  double ep = 0.0;
  #pragma unroll
  for (int di = 0; di < 3; di++)
    #pragma unroll
    for (int dj = 0; dj < 3; dj++){
      int ci = i0+di, cj = j0+dj;
      if (ci < NCW && cj < NCW){
        float sig = S[di+1][dj+1];
        float u00 = U[di][dj], uE = U[di+1][dj], uN = U[di][dj+1], uNE = U[di+1][dj+1];
        float gxA = uE - u00, gyA = uN - u00;
        float gxB = -2.f*uE + uNE + uN, gyB = uE - uNE;
        ep += (double)(sig * 0.5f * (gxA*gxA + gyA*gyA + gxB*gxB + gyB*gyB));
      }
    }
  {
    double dummy = 0.0;
    dual_warp_red(ep, dummy);
    if (lane == 0) pA[wid] = ep;
  }
  __syncthreads();
  if (tid == 0) out[0] = (float)sum16_tree(pA);
}

extern "C" void kernel_launch(void* const* d_in, const int* in_sizes, int n_in,
                              void* d_out, int out_size, void* d_ws, size_t ws_size,
                              hipStream_t stream){
  (void)d_ws; (void)ws_size; (void)out_size;
  int mi = 0;
  for (int k = 0; k < n_in; k++) if (in_sizes[k] == 9025) { mi = k; break; }
  const float* mask = (const float*)d_in[mi];
  fem_mgcg_kernel<<<dim3(1), dim3(NTHREADS), 0, stream>>>(mask, (float*)d_out);
}